// Round 8
// baseline (124.191 us; speedup 1.0000x reference)
//
#include <hip/hip_runtime.h>
#include <math.h>

// Problem constants
#define NXD 64
#define NYD 48
#define NZD 32
#define NPT (NXD*NYD*NZD)   // 98304 points
#define PN  10              // neighbors per point
#define MF  5               // fourier modes
#define H1  64
#define H2  32
#define H3  8

// Block geometry: 256 threads = 4 waves; 3 chunks x 32 points per block.
// Per chunk: 320 rows; each wave owns 8 points = 80 rows = 5 tiles of 16 rows,
// processed as 2 pipelined pairs + 1 tail tile (2-tile ILP).
// 1024 blocks x 33.8KB LDS -> 4 blocks/CU ALL resident; weight prologue paid 1x/3 chunks.
#define PTS_PER_BLOCK 32
#define CHUNKS 3
#define ROWS_PER_BLOCK (PTS_PER_BLOCK*PN)   // 320 per chunk
#define TILES_PER_WAVE 5

// LDS strides (f16 elements) — row stride multiple of 8 (16B) for ds_read_b128
#define A2S 72   // 16 rows x 72 (64 ch + pad)
#define A3S 40   // 16 rows x 40 (32 ch + pad) — ALIASED into a2buf's space

#define INV2PI 0.15915494309189535f

typedef __attribute__((ext_vector_type(8))) _Float16 half8;   // 8 f16 = 4 VGPRs
typedef __attribute__((ext_vector_type(2))) _Float16 half2v;
typedef __attribute__((ext_vector_type(2))) __fp16   fp16x2;  // cvt_pkrtz return type
typedef __attribute__((ext_vector_type(2))) short    shortv2;
typedef __attribute__((ext_vector_type(4))) float    f32x4;

// pack two f32 -> half2v via v_cvt_pkrtz_f16_f32 (1 instr), bit-cast to _Float16 vec
__device__ __forceinline__ half2v cvt_pk_h2(float lo, float hi) {
    fp16x2 p = __builtin_amdgcn_cvt_pkrtz(lo, hi);
    return __builtin_bit_cast(half2v, p);
}

// Per-(lg,j) feature descriptor for the PERMUTED K-ordering of layer 1.
//   lg0: [x,   s0x,s1x,s2x,s3x,s4x, c0x,c1x]            (cA=x, cB=x)
//   lg1: [y,   c2x,c3x,c4x, s0y,s1y,s2y,s3y]            (cA=x, cB=y)
//   lg2: [z,   s4y, c0y,c1y,c2y,c3y,c4y, s0z]           (cA=y, cB=z)
//   lg3: [s1z,s2z,s3z,s4z, c0z,c1z,c2z,c3z]             (cA=z, cB=z)
// leftover channel 32 = c4z (rank-1 fixup).
// encoding: row(6b) | m(3b)<<6 | path(1b)<<9 | type(2b)<<10  (0=sin,1=cos,2=raw)
static __device__ const unsigned short kSlotTab[32] = {
  2048,    3,   70,  137,  204,  271, 1042, 1109,   // lg0
  2561, 1176, 1243, 1310,  516,  583,  650,  717,   // lg1
  2562,  272, 1043, 1110, 1177, 1244, 1311,  517,   // lg2
    72,  139,  206,  273, 1044, 1111, 1178, 1245 }; // lg3

// hardware f16 exp2 (trans pipe, 1 instr)
__device__ __forceinline__ _Float16 exp2h(_Float16 v) {
    _Float16 r;
    asm("v_exp_f16 %0, %1" : "=v"(r) : "v"(v));
    return r;
}

// Packed-f16 GELU on a pair of f32 pre-activations.
// gelu = x - x/(1+2^t), t = x*(2.3022082 + 0.10294324 x^2)  [tanh-form, log2e folded]
// reciprocal via f16 bit-trick guess (0x7800 - bits(y); exact at y=1,2; max err 12.5%)
// + 2 Newton steps -> 2.4e-4 rel. t clamped <=14 keeps y=1+2^t normal f16;
// t very negative -> E=0 -> y=1 -> r=1 -> gelu=0 exactly. 13 VALU + 2 trans per PAIR.
__device__ __forceinline__ half2v gelu_pk(float lo, float hi) {
    const _Float16 C1 = (_Float16)2.3022082f, C2 = (_Float16)0.10294324f;
    const half2v x  = cvt_pk_h2(lo, hi);
    const half2v x2 = x * x;
    half2v t = x * __builtin_elementwise_fma(x2, (half2v){C2, C2}, (half2v){C1, C1});
    t = __builtin_elementwise_min(t, (half2v){(_Float16)14.0f, (_Float16)14.0f});
    const _Float16 e0 = exp2h(t[0]);
    const _Float16 e1 = exp2h(t[1]);
    const half2v one = {(_Float16)1.0f, (_Float16)1.0f};
    const half2v two = {(_Float16)2.0f, (_Float16)2.0f};
    const half2v y = (half2v){e0, e1} + one;
    const shortv2 rb = (shortv2){(short)0x7800, (short)0x7800} - __builtin_bit_cast(shortv2, y);
    half2v r = __builtin_bit_cast(half2v, rb);
    r = r * __builtin_elementwise_fma(-y, r, two);
    r = r * __builtin_elementwise_fma(-y, r, two);
    return x - x * r;
}

// tanh via 2^x: 1 - 2/(1+2^{2*log2e*v}); safe at both infinities
__device__ __forceinline__ float tanh_fast(float v) {
    float E = __builtin_amdgcn_exp2f(2.8853901f * v);
    return 1.0f - 2.0f * __builtin_amdgcn_rcpf(E + 1.0f);
}

__global__ __launch_bounds__(256, 4) void domino_mfma_kernel(
    const float* __restrict__ x,      // (NPT*PN, 3)
    const float* __restrict__ freqs,  // (MF,)
    const float* __restrict__ W1,     // (33, 64)
    const float* __restrict__ b1,
    const float* __restrict__ W2,     // (64, 32)
    const float* __restrict__ b2,
    const float* __restrict__ W3,     // (32, 8)
    const float* __restrict__ b3,
    float* __restrict__ out)          // (8, NPT)
{
    // LDS budget (sum 33792 B -> 4 blocks/CU = 16 waves/CU, all resident at grid=1024):
    __shared__ __align__(16) _Float16 a2buf[4][2][16 * A2S];    // 18432 B; low bytes alias a3
    __shared__ __align__(16) float cbuf[2][976];                // 7808 B staged coords (dbuf)
    __shared__ __align__(16) _Float16 obuf[ROWS_PER_BLOCK * 9]; // 5760 B masked tanh rows
    __shared__ __align__(16) float mcx[4][2][16];               // x-coordinate per row (mask)
    __shared__ __align__(16) float mv32[4][2][16];              // feature ch32 = cos(f4*z)
    __shared__ __align__(16) float coefA[2][32];                // (x2 copies: (tp&1) anti-hoist)
    __shared__ __align__(16) float coefB[2][32];
    __shared__ __align__(16) float coefO[2][32];

    const int tid  = threadIdx.x;
    const int w    = tid >> 6;      // wave id 0..3
    const int lane = tid & 63;
    const int lr   = lane & 15;     // A-row / B-col / C-col index
    const int lg   = lane >> 4;     // k-group / C-row-group

    // ---- coord staging: one global_load_lds dwordx4 per wave per chunk (960 B).
    // Lanes 60-63 are redundant overflow (identical data or clamped into slack).
    auto stage_coords = [&](int c, int buf) {
        const int row0 = (blockIdx.x*CHUNKS + c) * ROWS_PER_BLOCK + w*(TILES_PER_WAVE*16);
        const int sl = (w == 3 && lane >= 60) ? 59 : lane;
        const float* gsrc = x + (size_t)row0 * 3 + (size_t)sl * 4;
        __builtin_amdgcn_global_load_lds(
            (const __attribute__((address_space(1))) void*)gsrc,
            (__attribute__((address_space(3))) void*)&cbuf[buf][w * 240], 16, 0, 0);
    };

    // ---- fill per-lg coefficient tables (32 threads; duplicated for (tp&1) indexing)
    if (tid < 32) {
        const unsigned e = kSlotTab[tid];
        const int m = (e >> 6) & 7, path = (e >> 9) & 1, ty = (e >> 10) & 3;
        const float fm = freqs[m] * INV2PI;
        const float fa = (ty != 2 && path == 0) ? fm : 0.0f;
        const float fb = (ty != 2 && path == 1) ? fm : 0.0f;
        const float fo = (ty == 1) ? 0.25f : 0.0f;
        coefA[0][tid] = fa; coefA[1][tid] = fa;
        coefB[0][tid] = fb; coefB[1][tid] = fb;
        coefO[0][tid] = fo; coefO[1][tid] = fo;
    }

    stage_coords(0, 0);   // chunk 0 coords overlap the weight prologue below

    const float f4rev = freqs[4] * INV2PI;
    const float rawf  = (lg < 3) ? 1.0f : 0.0f;   // slot0 is a raw coordinate for lg0..2

    // ---- preload weight fragments as f16 (ONCE per block, amortized over 3 chunks)
    half8 B1f[4];                       // layer1: K=32 (permuted), N=64 -> 4 n-tiles
    float  w32[4], bv1[4];              // ch32 rank-1 fixup weights + bias
    #pragma unroll
    for (int t1 = 0; t1 < 4; ++t1) {
        #pragma unroll
        for (int j = 0; j < 8; ++j) {
            const int row = kSlotTab[lg*8 + j] & 63;
            B1f[t1][j] = (_Float16)W1[row*H1 + t1*16 + lr];
        }
        w32[t1] = W1[32*H1 + t1*16 + lr];
        bv1[t1] = b1[t1*16 + lr];
    }
    half8 B2f[2][2];                    // layer2: K=64 (2 steps), N=32 -> 2 n-tiles
    float  bv2[2];
    #pragma unroll
    for (int s = 0; s < 2; ++s)
        #pragma unroll
        for (int t2 = 0; t2 < 2; ++t2)
            #pragma unroll
            for (int j = 0; j < 8; ++j)
                B2f[s][t2][j] = (_Float16)W2[(s*32 + lg*8 + j)*H2 + t2*16 + lr];
    #pragma unroll
    for (int t2 = 0; t2 < 2; ++t2) bv2[t2] = b2[t2*16 + lr];

    half8 B3f;                          // layer3: K=32, N=16 (cols 8..15 zero)
    float  bv3 = (lr < H3) ? b3[lr] : 0.0f;
    #pragma unroll
    for (int j = 0; j < 8; ++j)
        B3f[j] = (lr < H3) ? (_Float16)W3[(lg*8 + j)*H3 + lr] : (_Float16)0.0f;

    // tables + chunk-0 coords visible (implies vmcnt/lgkmcnt drain)
    __syncthreads();

    // ================= phase helpers (inlined; u is always a literal) =================
    auto featgen = [&](const float* cbp, int t, int u,
                       const f32x4& fa0, const f32x4& fb0, const f32x4& fo0,
                       const f32x4& fa1, const f32x4& fb1, const f32x4& fo1) -> half8 {
        const int cfx = w*240 + (t*16 + lr)*3;
        const float cx = cbp[cfx + 0];
        const float cy = cbp[cfx + 1];
        const float cz = cbp[cfx + 2];
        const float cA = (lg <= 1) ? cx : ((lg == 2) ? cy : cz);
        const float cB = (lg == 0) ? cx : ((lg == 1) ? cy : cz);
        float fv[8];
        #pragma unroll
        for (int j = 0; j < 4; ++j) {
            float rev = cA*fa0[j] + (cB*fb0[j] + fo0[j]);
            fv[j] = __builtin_amdgcn_sinf(__builtin_amdgcn_fractf(rev));
        }
        #pragma unroll
        for (int j = 0; j < 4; ++j) {
            float rev = cA*fa1[j] + (cB*fb1[j] + fo1[j]);
            fv[4+j] = __builtin_amdgcn_sinf(__builtin_amdgcn_fractf(rev));
        }
        fv[0] += rawf * (cB - fv[0]);   // slot0 raw-coordinate override (no-op for lg3)
        if (lg == 0) {
            mcx[w][u][lr]  = cx;
            mv32[w][u][lr] = __builtin_amdgcn_sinf(__builtin_amdgcn_fractf(cz * f4rev + 0.25f));
        }
        union { half2v h2[4]; half8 h8; } a1u;
        #pragma unroll
        for (int j = 0; j < 4; ++j)
            a1u.h2[j] = cvt_pk_h2(fv[2*j], fv[2*j+1]);
        return a1u.h8;
    };

    auto layer1 = [&](const half8& a1, f32x4* c1, int u) {
        #pragma unroll
        for (int t1 = 0; t1 < 4; ++t1) {
            f32x4 ci = {bv1[t1], bv1[t1], bv1[t1], bv1[t1]};
            c1[t1] = __builtin_amdgcn_mfma_f32_16x16x32_f16(a1, B1f[t1], ci, 0, 0, 0);
        }
        const f32x4 v32r = *(const f32x4*)&mv32[w][u][lg*4];
        #pragma unroll
        for (int t1 = 0; t1 < 4; ++t1)
            #pragma unroll
            for (int r = 0; r < 4; ++r)
                c1[t1][r] += v32r[r] * w32[t1];
    };

    auto gelu_a2 = [&](const f32x4* c1, int u) {
        _Float16* const buf = &a2buf[w][u][0];
        #pragma unroll
        for (int t1 = 0; t1 < 4; ++t1) {
            const half2v g01 = gelu_pk(c1[t1][0], c1[t1][1]);
            const half2v g23 = gelu_pk(c1[t1][2], c1[t1][3]);
            const int col = t1*16 + lr;
            buf[(lg*4 + 0)*A2S + col] = g01[0];
            buf[(lg*4 + 1)*A2S + col] = g01[1];
            buf[(lg*4 + 2)*A2S + col] = g23[0];
            buf[(lg*4 + 3)*A2S + col] = g23[1];
        }
    };

    auto read_a2 = [&](int u, half8* a2f) {
        #pragma unroll
        for (int s = 0; s < 2; ++s)
            a2f[s] = *(const half8*)&a2buf[w][u][lr*A2S + s*32 + lg*8];
    };

    auto layer2 = [&](const half8* a2f, f32x4* c2) {
        #pragma unroll
        for (int t2 = 0; t2 < 2; ++t2) {
            f32x4 ci = {bv2[t2], bv2[t2], bv2[t2], bv2[t2]};
            ci = __builtin_amdgcn_mfma_f32_16x16x32_f16(a2f[0], B2f[0][t2], ci, 0, 0, 0);
            c2[t2] = __builtin_amdgcn_mfma_f32_16x16x32_f16(a2f[1], B2f[1][t2], ci, 0, 0, 0);
        }
    };

    // a3 region ALIASES a2buf[w][u] rows 0..8: safe — a2f reads completed (data-dep
    // through L2 MFMA) before these writes issue; same-wave LDS ops are in-order.
    auto gelu_a3 = [&](const f32x4* c2, int u) {
        _Float16* const a3p = &a2buf[w][u][0];
        #pragma unroll
        for (int t2 = 0; t2 < 2; ++t2) {
            const half2v g01 = gelu_pk(c2[t2][0], c2[t2][1]);
            const half2v g23 = gelu_pk(c2[t2][2], c2[t2][3]);
            const int col = t2*16 + lr;
            a3p[(lg*4 + 0)*A3S + col] = g01[0];
            a3p[(lg*4 + 1)*A3S + col] = g01[1];
            a3p[(lg*4 + 2)*A3S + col] = g23[0];
            a3p[(lg*4 + 3)*A3S + col] = g23[1];
        }
    };

    auto l3_tail = [&](int t, int u) {
        const half8 a3f = *(const half8*)&a2buf[w][u][lr*A3S + lg*8];
        f32x4 c3 = {bv3, bv3, bv3, bv3};
        c3 = __builtin_amdgcn_mfma_f32_16x16x32_f16(a3f, B3f, c3, 0, 0, 0);
        const f32x4 mxr = *(const f32x4*)&mcx[w][u][lg*4];
        #pragma unroll
        for (int r = 0; r < 4; ++r) {
            const int brow = w*(TILES_PER_WAVE*16) + t*16 + lg*4 + r;
            const float mk = (fabsf(mxr[r]) > 1e-6f) ? 1.0f : 0.0f;
            if (lr < H3) obuf[brow*9 + lr] = (_Float16)(mk * tanh_fast(c3[r]));
        }
    };

    // ================= chunk loop =================
    #pragma unroll 1
    for (int c = 0; c < CHUNKS; ++c) {
        if (c + 1 < CHUNKS) stage_coords(c + 1, (c + 1) & 1);  // hides under this chunk
        const float* cbp = &cbuf[c & 1][0];

        // ---- 2-tile pipelined pairs: (0,1), (2,3)
        #pragma unroll 1
        for (int tp = 0; tp < 2; ++tp) {
            const int tc = tp & 1;   // runtime-indexed copy blocks coef LICM
            const f32x4 fa0 = *(const f32x4*)&coefA[tc][lg*8];
            const f32x4 fb0 = *(const f32x4*)&coefB[tc][lg*8];
            const f32x4 fo0 = *(const f32x4*)&coefO[tc][lg*8];
            const f32x4 fa1 = *(const f32x4*)&coefA[tc][lg*8 + 4];
            const f32x4 fb1 = *(const f32x4*)&coefB[tc][lg*8 + 4];
            const f32x4 fo1 = *(const f32x4*)&coefO[tc][lg*8 + 4];

            const half8 a1a = featgen(cbp, 2*tp + 0, 0, fa0, fb0, fo0, fa1, fb1, fo1);
            const half8 a1b = featgen(cbp, 2*tp + 1, 1, fa0, fb0, fo0, fa1, fb1, fo1);

            f32x4 c1a[4], c1b[4];
            layer1(a1a, c1a, 0);
            layer1(a1b, c1b, 1);

            gelu_a2(c1a, 0);
            gelu_a2(c1b, 1);

            half8 a2fa[2], a2fb[2];
            read_a2(0, a2fa);
            read_a2(1, a2fb);

            f32x4 c2a[2], c2b[2];
            layer2(a2fa, c2a);
            layer2(a2fb, c2b);

            gelu_a3(c2a, 0);
            gelu_a3(c2b, 1);

            l3_tail(2*tp + 0, 0);
            l3_tail(2*tp + 1, 1);
        }

        // ---- tail tile 4 (single stream)
        {
            const f32x4 fa0 = *(const f32x4*)&coefA[0][lg*8];
            const f32x4 fb0 = *(const f32x4*)&coefB[0][lg*8];
            const f32x4 fo0 = *(const f32x4*)&coefO[0][lg*8];
            const f32x4 fa1 = *(const f32x4*)&coefA[0][lg*8 + 4];
            const f32x4 fb1 = *(const f32x4*)&coefB[0][lg*8 + 4];
            const f32x4 fo1 = *(const f32x4*)&coefO[0][lg*8 + 4];

            const half8 a1t = featgen(cbp, 4, 0, fa0, fb0, fo0, fa1, fb1, fo1);
            f32x4 c1t[4];
            layer1(a1t, c1t, 0);
            gelu_a2(c1t, 0);
            half8 a2ft[2];
            read_a2(0, a2ft);
            f32x4 c2t[2];
            layer2(a2ft, c2t);
            gelu_a3(c2t, 0);
            l3_tail(4, 0);
        }

        // ---- all obuf rows of this chunk written (also drains the prefetch vmcnt)
        __syncthreads();

        // ---- neighbor reduction: 32 points x 8 channels = 256 threads
        {
            const int p  = tid >> 3;   // 0..31
            const int ch = tid & 7;
            float sum = 0.0f;
            #pragma unroll
            for (int i = 0; i < PN; ++i) sum += (float)obuf[(p*PN + i)*9 + ch];
            const int gp = blockIdx.x * (PTS_PER_BLOCK*CHUNKS) + c*PTS_PER_BLOCK + p;
            out[(size_t)ch * NPT + gp] = sum;
        }

        // ---- protect obuf from next chunk's writes
        if (c + 1 < CHUNKS) __syncthreads();
    }
}

extern "C" void kernel_launch(void* const* d_in, const int* in_sizes, int n_in,
                              void* d_out, int out_size, void* d_ws, size_t ws_size,
                              hipStream_t stream) {
    // setup_inputs order: x, grid(unused), freqs, W1, b1, W2, b2, W3, b3
    const float* x     = (const float*)d_in[0];
    const float* freqs = (const float*)d_in[2];
    const float* W1    = (const float*)d_in[3];
    const float* b1    = (const float*)d_in[4];
    const float* W2    = (const float*)d_in[5];
    const float* b2    = (const float*)d_in[6];
    const float* W3    = (const float*)d_in[7];
    const float* b3    = (const float*)d_in[8];
    float* out = (float*)d_out;

    const int grid = NPT / (PTS_PER_BLOCK * CHUNKS);   // 1024 blocks, no remainder
    domino_mfma_kernel<<<grid, 256, 0, stream>>>(x, freqs, W1, b1, W2, b2, W3, b3, out);
}

// Round 9
// 121.243 us; speedup vs baseline: 1.0243x; 1.0243x over previous
//
#include <hip/hip_runtime.h>
#include <math.h>

// Problem constants
#define NXD 64
#define NYD 48
#define NZD 32
#define NPT (NXD*NYD*NZD)   // 98304 points
#define PN  10              // neighbors per point
#define MF  5               // fourier modes
#define H1  64
#define H2  32
#define H3  8

// Block geometry: 256 threads = 4 waves; 3 chunks x 32 points per block.
// Per chunk: 320 rows; each wave owns 8 points = 80 rows = 5 tiles of 16 rows.
// SWAPPED-OPERAND dataflow: mfma(W_frag, X_frag) computes H^T, so each lane holds
// point=lr and channel-rows; with K-permutations pi2/pi3 chosen so each lane's
// layer-(n+1) A-fragment is ITS OWN registers, the LDS transposes vanish entirely.
#define PTS_PER_BLOCK 32
#define CHUNKS 3
#define ROWS_PER_BLOCK (PTS_PER_BLOCK*PN)   // 320 per chunk
#define TILES_PER_WAVE 5

#define INV2PI 0.15915494309189535f

typedef __attribute__((ext_vector_type(8))) _Float16 half8;   // 8 f16 = 4 VGPRs
typedef __attribute__((ext_vector_type(2))) _Float16 half2v;
typedef __attribute__((ext_vector_type(2))) __fp16   fp16x2;  // cvt_pkrtz return type
typedef __attribute__((ext_vector_type(2))) short    shortv2;
typedef __attribute__((ext_vector_type(4))) float    f32x4;

// pack two f32 -> half2v via v_cvt_pkrtz_f16_f32 (1 instr), bit-cast to _Float16 vec
__device__ __forceinline__ half2v cvt_pk_h2(float lo, float hi) {
    fp16x2 p = __builtin_amdgcn_cvt_pkrtz(lo, hi);
    return __builtin_bit_cast(half2v, p);
}

// Per-(lg,j) feature descriptor for the PERMUTED K-ordering of layer 1.
//   lg0: [x,   s0x,s1x,s2x,s3x,s4x, c0x,c1x]            (cA=x, cB=x)
//   lg1: [y,   c2x,c3x,c4x, s0y,s1y,s2y,s3y]            (cA=x, cB=y)
//   lg2: [z,   s4y, c0y,c1y,c2y,c3y,c4y, s0z]           (cA=y, cB=z)
//   lg3: [s1z,s2z,s3z,s4z, c0z,c1z,c2z,c3z]             (cA=z, cB=z)
// leftover channel 32 = c4z (rank-1 fixup).
// encoding: row(6b) | m(3b)<<6 | path(1b)<<9 | type(2b)<<10  (0=sin,1=cos,2=raw)
static __device__ const unsigned short kSlotTab[32] = {
  2048,    3,   70,  137,  204,  271, 1042, 1109,   // lg0
  2561, 1176, 1243, 1310,  516,  583,  650,  717,   // lg1
  2562,  272, 1043, 1110, 1177, 1244, 1311,  517,   // lg2
    72,  139,  206,  273, 1044, 1111, 1178, 1245 }; // lg3

// hardware f16 exp2 (trans pipe, 1 instr)
__device__ __forceinline__ _Float16 exp2h(_Float16 v) {
    _Float16 r;
    asm("v_exp_f16 %0, %1" : "=v"(r) : "v"(v));
    return r;
}

// Packed-f16 GELU on a pair of f32 pre-activations.
// gelu = x - x/(1+2^t), t = x*(2.3022082 + 0.10294324 x^2)  [tanh-form, log2e folded]
// reciprocal via f16 bit-trick guess (0x7800 - bits(y); exact at y=1,2; max err 12.5%)
// + 2 Newton steps -> 2.4e-4 rel. t clamped <=14 keeps y=1+2^t normal f16;
// t very negative -> E=0 -> y=1 -> r=1 -> gelu=0 exactly. 13 VALU + 2 trans per PAIR.
__device__ __forceinline__ half2v gelu_pk(float lo, float hi) {
    const _Float16 C1 = (_Float16)2.3022082f, C2 = (_Float16)0.10294324f;
    const half2v x  = cvt_pk_h2(lo, hi);
    const half2v x2 = x * x;
    half2v t = x * __builtin_elementwise_fma(x2, (half2v){C2, C2}, (half2v){C1, C1});
    t = __builtin_elementwise_min(t, (half2v){(_Float16)14.0f, (_Float16)14.0f});
    const _Float16 e0 = exp2h(t[0]);
    const _Float16 e1 = exp2h(t[1]);
    const half2v one = {(_Float16)1.0f, (_Float16)1.0f};
    const half2v two = {(_Float16)2.0f, (_Float16)2.0f};
    const half2v y = (half2v){e0, e1} + one;
    const shortv2 rb = (shortv2){(short)0x7800, (short)0x7800} - __builtin_bit_cast(shortv2, y);
    half2v r = __builtin_bit_cast(half2v, rb);
    r = r * __builtin_elementwise_fma(-y, r, two);
    r = r * __builtin_elementwise_fma(-y, r, two);
    return x - x * r;
}

// tanh via 2^x: 1 - 2/(1+2^{2*log2e*v}); safe at both infinities (f32, as in R8)
__device__ __forceinline__ float tanh_fast(float v) {
    float E = __builtin_amdgcn_exp2f(2.8853901f * v);
    return 1.0f - 2.0f * __builtin_amdgcn_rcpf(E + 1.0f);
}

__global__ __launch_bounds__(256) void domino_mfma_kernel(
    const float* __restrict__ x,      // (NPT*PN, 3)
    const float* __restrict__ freqs,  // (MF,)
    const float* __restrict__ W1,     // (33, 64)
    const float* __restrict__ b1,
    const float* __restrict__ W2,     // (64, 32)
    const float* __restrict__ b2,
    const float* __restrict__ W3,     // (32, 8)
    const float* __restrict__ b3,
    float* __restrict__ out)          // (8, NPT)
{
    // LDS budget (~14.4 KB; no transpose buffers anymore):
    __shared__ __align__(16) float cbuf[2][976];                // 7808 B staged coords (dbuf)
    __shared__ __align__(16) _Float16 obuf[ROWS_PER_BLOCK * 9]; // 5760 B masked tanh rows
    __shared__ __align__(16) float coefA[2][32];                // (x2 copies: (t&1) anti-hoist)
    __shared__ __align__(16) float coefB[2][32];
    __shared__ __align__(16) float coefO[2][32];

    const int tid  = threadIdx.x;
    const int w    = tid >> 6;      // wave id 0..3
    const int lane = tid & 63;
    const int lr   = lane & 15;     // point index (n-col of swapped MFMA)
    const int lg   = lane >> 4;     // k-group / channel-row group

    // ---- coord staging: one global_load_lds dwordx4 per wave per chunk (960 B).
    auto stage_coords = [&](int c, int buf) {
        const int row0 = (blockIdx.x*CHUNKS + c) * ROWS_PER_BLOCK + w*(TILES_PER_WAVE*16);
        const int sl = (w == 3 && lane >= 60) ? 59 : lane;
        const float* gsrc = x + (size_t)row0 * 3 + (size_t)sl * 4;
        __builtin_amdgcn_global_load_lds(
            (const __attribute__((address_space(1))) void*)gsrc,
            (__attribute__((address_space(3))) void*)&cbuf[buf][w * 240], 16, 0, 0);
    };

    // ---- fill per-lg coefficient tables (32 threads; duplicated for (t&1) indexing)
    if (tid < 32) {
        const unsigned e = kSlotTab[tid];
        const int m = (e >> 6) & 7, path = (e >> 9) & 1, ty = (e >> 10) & 3;
        const float fm = freqs[m] * INV2PI;
        const float fa = (ty != 2 && path == 0) ? fm : 0.0f;
        const float fb = (ty != 2 && path == 1) ? fm : 0.0f;
        const float fo = (ty == 1) ? 0.25f : 0.0f;
        coefA[0][tid] = fa; coefA[1][tid] = fa;
        coefB[0][tid] = fb; coefB[1][tid] = fb;
        coefO[0][tid] = fo; coefO[1][tid] = fo;
    }

    stage_coords(0, 0);   // chunk 0 coords overlap the weight prologue below

    const float f4rev = freqs[4] * INV2PI;
    const float rawf  = (lg < 3) ? 1.0f : 0.0f;   // slot0 is a raw coordinate for lg0..2

    // ---- weight fragments for SWAPPED mfma (W as A-operand: m=lane&15=out-channel).
    // Layer1: B1f[t1][j] = W1[pi1(lg,j)][t1*16+lr]  (pi1 = kSlotTab feature permutation)
    half8 B1f[4];
    f32x4 w32s[4], bv1s[4];             // ch32 rank-1 fixup + bias, per-lane 4 channel-rows
    #pragma unroll
    for (int t1 = 0; t1 < 4; ++t1) {
        #pragma unroll
        for (int j = 0; j < 8; ++j) {
            const int row = kSlotTab[lg*8 + j] & 63;
            B1f[t1][j] = (_Float16)W1[row*H1 + t1*16 + lr];
        }
        #pragma unroll
        for (int r = 0; r < 4; ++r) {
            w32s[t1][r] = W1[32*H1 + t1*16 + lg*4 + r];
            bv1s[t1][r] = b1[t1*16 + lg*4 + r];
        }
    }
    // Layer2: K-permutation pi2(q,s,j) = (2q+(j>>2))*16 + 4s + (j&3) makes each lane's
    // A2-fragment exactly its own L1 outputs. B2f[q][t2][j] = W2[pi2][t2*16+lr].
    half8 B2f[2][2];
    f32x4 bv2s[2];
    #pragma unroll
    for (int q = 0; q < 2; ++q)
        #pragma unroll
        for (int t2 = 0; t2 < 2; ++t2)
            #pragma unroll
            for (int j = 0; j < 8; ++j)
                B2f[q][t2][j] = (_Float16)W2[((2*q + (j>>2))*16 + lg*4 + (j&3))*H2 + t2*16 + lr];
    #pragma unroll
    for (int t2 = 0; t2 < 2; ++t2)
        #pragma unroll
        for (int r = 0; r < 4; ++r)
            bv2s[t2][r] = b2[t2*16 + lg*4 + r];

    // Layer3: pi3(s,j) = (j>>2)*16 + 4s + (j&3); N=16 points, M rows: 8 valid out-chs.
    half8 B3f;
    #pragma unroll
    for (int j = 0; j < 8; ++j)
        B3f[j] = (lr < H3) ? (_Float16)W3[((j>>2)*16 + lg*4 + (j&3))*H3 + lr] : (_Float16)0.0f;
    f32x4 bv3s;
    #pragma unroll
    for (int r = 0; r < 4; ++r)
        bv3s[r] = (lg < 2) ? b3[lg*4 + r] : 0.0f;

    // tables + chunk-0 coords visible (implies vmcnt/lgkmcnt drain)
    __syncthreads();

    // ================= chunk loop =================
    #pragma unroll 1
    for (int c = 0; c < CHUNKS; ++c) {
        if (c + 1 < CHUNKS) stage_coords(c + 1, (c + 1) & 1);  // hides under this chunk
        const float* cbp = &cbuf[c & 1][0];

        #pragma unroll 1
        for (int t = 0; t < TILES_PER_WAVE; ++t) {
            const int tc = t & 1;
            // ---- coords of point lr (4 lane-groups broadcast)
            const int cfx = w*240 + (t*16 + lr)*3;
            const float cx = cbp[cfx + 0];
            const float cy = cbp[cfx + 1];
            const float cz = cbp[cfx + 2];
            const float cA = (lg <= 1) ? cx : ((lg == 2) ? cy : cz);
            const float cB = (lg == 0) ? cx : ((lg == 1) ? cy : cz);

            // ---- 8 features: 2 fma + fract + v_sin each
            float fv[8];
            {
                const f32x4 fa0 = *(const f32x4*)&coefA[tc][lg*8];
                const f32x4 fb0 = *(const f32x4*)&coefB[tc][lg*8];
                const f32x4 fo0 = *(const f32x4*)&coefO[tc][lg*8];
                #pragma unroll
                for (int j = 0; j < 4; ++j) {
                    float rev = cA*fa0[j] + (cB*fb0[j] + fo0[j]);
                    fv[j] = __builtin_amdgcn_sinf(__builtin_amdgcn_fractf(rev));
                }
                const f32x4 fa1 = *(const f32x4*)&coefA[tc][lg*8 + 4];
                const f32x4 fb1 = *(const f32x4*)&coefB[tc][lg*8 + 4];
                const f32x4 fo1 = *(const f32x4*)&coefO[tc][lg*8 + 4];
                #pragma unroll
                for (int j = 0; j < 4; ++j) {
                    float rev = cA*fa1[j] + (cB*fb1[j] + fo1[j]);
                    fv[4+j] = __builtin_amdgcn_sinf(__builtin_amdgcn_fractf(rev));
                }
            }
            fv[0] += rawf * (cB - fv[0]);   // slot0 raw-coordinate override (no-op lg3)

            // ch32 feature (cos f4*z) of THIS lane's point — all 4 lanes compute it
            const float v32 = __builtin_amdgcn_sinf(__builtin_amdgcn_fractf(cz * f4rev + 0.25f));

            // ---- pack features: B-operand fragment (n=lr=point, k=lg*8+j)
            union { half2v h2[4]; half8 h8; } a1u;
            #pragma unroll
            for (int j = 0; j < 4; ++j)
                a1u.h2[j] = cvt_pk_h2(fv[2*j], fv[2*j+1]);
            const half8 a1 = a1u.h8;

            // ---- Layer 1 SWAPPED: c1[t1][r] = H1[ch=t1*16+lg*4+r][point=lr]
            f32x4 c1[4];
            #pragma unroll
            for (int t1 = 0; t1 < 4; ++t1)
                c1[t1] = __builtin_amdgcn_mfma_f32_16x16x32_f16(B1f[t1], a1, bv1s[t1], 0, 0, 0);
            // rank-1 ch32 fixup: += v32(point) * W1[32][ch]
            #pragma unroll
            for (int t1 = 0; t1 < 4; ++t1)
                #pragma unroll
                for (int r = 0; r < 4; ++r)
                    c1[t1][r] += v32 * w32s[t1][r];

            // ---- gelu + pack IN REGISTERS: a2f[q][j] = g1[2q+(j>>2)][j&3]  (pi2)
            union { half2v h2[4]; half8 h8; } a2u0, a2u1;
            a2u0.h2[0] = gelu_pk(c1[0][0], c1[0][1]);
            a2u0.h2[1] = gelu_pk(c1[0][2], c1[0][3]);
            a2u0.h2[2] = gelu_pk(c1[1][0], c1[1][1]);
            a2u0.h2[3] = gelu_pk(c1[1][2], c1[1][3]);
            a2u1.h2[0] = gelu_pk(c1[2][0], c1[2][1]);
            a2u1.h2[1] = gelu_pk(c1[2][2], c1[2][3]);
            a2u1.h2[2] = gelu_pk(c1[3][0], c1[3][1]);
            a2u1.h2[3] = gelu_pk(c1[3][2], c1[3][3]);

            // ---- Layer 2 SWAPPED: K=64 via 2 q-steps
            f32x4 c2[2];
            #pragma unroll
            for (int t2 = 0; t2 < 2; ++t2) {
                f32x4 ci = __builtin_amdgcn_mfma_f32_16x16x32_f16(B2f[0][t2], a2u0.h8, bv2s[t2], 0, 0, 0);
                c2[t2]   = __builtin_amdgcn_mfma_f32_16x16x32_f16(B2f[1][t2], a2u1.h8, ci, 0, 0, 0);
            }

            // ---- gelu + pack: a3f[j] = g2[j>>2][j&3]  (pi3)
            union { half2v h2[4]; half8 h8; } a3u;
            a3u.h2[0] = gelu_pk(c2[0][0], c2[0][1]);
            a3u.h2[1] = gelu_pk(c2[0][2], c2[0][3]);
            a3u.h2[2] = gelu_pk(c2[1][0], c2[1][1]);
            a3u.h2[3] = gelu_pk(c2[1][2], c2[1][3]);

            // ---- Layer 3 SWAPPED: lane holds point=lr, out-chs lg*4+r (valid lg<2)
            f32x4 c3 = __builtin_amdgcn_mfma_f32_16x16x32_f16(B3f, a3u.h8, bv3s, 0, 0, 0);

            // ---- tanh, mask (cx kept in register), store per-point rows
            const float mk = (fabsf(cx) > 1e-6f) ? 1.0f : 0.0f;
            if (lg < 2) {
                const int base = (w*(TILES_PER_WAVE*16) + t*16 + lr)*9 + lg*4;
                #pragma unroll
                for (int r = 0; r < 4; ++r)
                    obuf[base + r] = (_Float16)(mk * tanh_fast(c3[r]));
            }
        }

        // ---- all obuf rows of this chunk written (also drains the prefetch vmcnt)
        __syncthreads();

        // ---- neighbor reduction: 32 points x 8 channels = 256 threads
        {
            const int p  = tid >> 3;   // 0..31
            const int ch = tid & 7;
            float sum = 0.0f;
            #pragma unroll
            for (int i = 0; i < PN; ++i) sum += (float)obuf[(p*PN + i)*9 + ch];
            const int gp = blockIdx.x * (PTS_PER_BLOCK*CHUNKS) + c*PTS_PER_BLOCK + p;
            out[(size_t)ch * NPT + gp] = sum;
        }

        // ---- protect obuf from next chunk's writes
        if (c + 1 < CHUNKS) __syncthreads();
    }
}

extern "C" void kernel_launch(void* const* d_in, const int* in_sizes, int n_in,
                              void* d_out, int out_size, void* d_ws, size_t ws_size,
                              hipStream_t stream) {
    // setup_inputs order: x, grid(unused), freqs, W1, b1, W2, b2, W3, b3
    const float* x     = (const float*)d_in[0];
    const float* freqs = (const float*)d_in[2];
    const float* W1    = (const float*)d_in[3];
    const float* b1    = (const float*)d_in[4];
    const float* W2    = (const float*)d_in[5];
    const float* b2    = (const float*)d_in[6];
    const float* W3    = (const float*)d_in[7];
    const float* b3    = (const float*)d_in[8];
    float* out = (float*)d_out;

    const int grid = NPT / (PTS_PER_BLOCK * CHUNKS);   // 1024 blocks, no remainder
    domino_mfma_kernel<<<grid, 256, 0, stream>>>(x, freqs, W1, b1, W2, b2, W3, b3, out);
}